// Round 7
// baseline (334.041 us; speedup 1.0000x reference)
//
#include <hip/hip_runtime.h>
#include <math.h>

// Problem constants: B=32, T=2048, H=512, D=2H=1024
constexpr int B = 32;
constexpr int T = 2048;
constexpr int H = 512;
constexpr int D = 2 * H;            // 1024
constexpr int CPH  = 16;            // hsum chunks per batch
constexpr int RWH  = T / CPH;       // 128 rows per hpart block
constexpr int CPF  = 32;            // fused chunks per batch
constexpr int RWF  = T / CPF;       // 64 rows per fused block

// ---------------------------------------------------------------------------
// Kernel 1: hpart[b,c,d] = sum over 128 rows of h*mask2.  No atomics.
// Also zeroes the per-batch election counters used by k_fused (visible to
// k_fused across the kernel boundary).
// grid = B*CPH = 512 blocks, 256 threads, thread owns float4 col tid.
// ---------------------------------------------------------------------------
__global__ void k_hpart(const float* __restrict__ h,
                        const float* __restrict__ mask,
                        float* __restrict__ hpart,
                        int* __restrict__ cnt) {
    if (blockIdx.x < B && threadIdx.x == 0) cnt[blockIdx.x] = 0;

    const int b   = blockIdx.x / CPH;
    const int c   = blockIdx.x % CPH;
    const int tid = threadIdx.x;
    const int t0  = c * RWH;

    const float4* hp = (const float4*)(h + ((size_t)b * T + t0) * D) + tid;
    const float4* mp = (const float4*)(mask + ((size_t)b * T + t0) * H) + (tid & 127);

    float4 acc = make_float4(0.f, 0.f, 0.f, 0.f);
    for (int t = 0; t < RWH; ++t) {
        float4 hv = hp[t * (D / 4)];
        float4 mv = mp[t * (H / 4)];
        acc.x += hv.x * mv.x;
        acc.y += hv.y * mv.y;
        acc.z += hv.z * mv.z;
        acc.w += hv.w * mv.w;
    }
    ((float4*)(hpart + (size_t)blockIdx.x * D))[tid] = acc;
}

// ---------------------------------------------------------------------------
// Kernel 2 (fused): reconstruct hsum from hpart (L2/L3-hit), single pass over
// lstm computing beta + online-softmax accumulation; 4-wave LDS merge ->
// ONE partial (m, s, racc[D]) per block.  The LAST block of each batch
// (device-scope atomic election) finalizes r[b,:] and alpha[b,:].
// grid = B*CPF = 1024 blocks, 256 threads (4 waves).
// ---------------------------------------------------------------------------
__global__ void k_fused(const float* __restrict__ lstm,
                        const float* __restrict__ hpart,
                        float* __restrict__ beta,
                        float* __restrict__ pm,
                        float* __restrict__ ps,
                        float* __restrict__ prb,
                        int* __restrict__ cnt,
                        float* __restrict__ r,
                        float* __restrict__ alpha) {
    const int b    = blockIdx.x / CPF;
    const int ch   = blockIdx.x % CPF;
    const int tid  = threadIdx.x;
    const int w    = tid >> 6;
    const int lane = tid & 63;

    __shared__ alignas(16) float lracc[4][D];   // 16 KB
    __shared__ float lms[8];
    __shared__ int elect;

    // hsum fragment for this lane's 16 columns: sum of CPH partial rows
    float4 hv[4] = {make_float4(0,0,0,0), make_float4(0,0,0,0),
                    make_float4(0,0,0,0), make_float4(0,0,0,0)};
    for (int p = 0; p < CPH; ++p) {
        const float4* pp = (const float4*)(hpart + (size_t)(b * CPH + p) * D);
#pragma unroll
        for (int k = 0; k < 4; ++k) {
            float4 v = pp[lane + 64 * k];
            hv[k].x += v.x; hv[k].y += v.y; hv[k].z += v.z; hv[k].w += v.w;
        }
    }

    float m = -INFINITY, s = 0.f;
    float4 racc[4] = {make_float4(0,0,0,0), make_float4(0,0,0,0),
                      make_float4(0,0,0,0), make_float4(0,0,0,0)};
    const int t0 = ch * RWF;
    for (int i = 0; i < RWF / 4; ++i) {
        const int t = t0 + i * 4 + w;
        const float4* lp = (const float4*)(lstm + ((size_t)b * T + t) * D);
        float4 lv[4];
#pragma unroll
        for (int k = 0; k < 4; ++k) lv[k] = lp[lane + 64 * k];

        float acc = 0.f;
#pragma unroll
        for (int k = 0; k < 4; ++k)
            acc += lv[k].x * hv[k].x + lv[k].y * hv[k].y +
                   lv[k].z * hv[k].z + lv[k].w * hv[k].w;
#pragma unroll
        for (int o = 32; o >= 1; o >>= 1) acc += __shfl_xor(acc, o, 64);
        if (lane == 0) beta[b * T + t] = acc;

        if (acc <= m) {            // wave-uniform branch (acc reduced)
            const float e = expf(acc - m);
            s += e;
#pragma unroll
            for (int k = 0; k < 4; ++k) {
                racc[k].x = fmaf(e, lv[k].x, racc[k].x);
                racc[k].y = fmaf(e, lv[k].y, racc[k].y);
                racc[k].z = fmaf(e, lv[k].z, racc[k].z);
                racc[k].w = fmaf(e, lv[k].w, racc[k].w);
            }
        } else {
            const float c2 = expf(m - acc);   // expf(-inf)=0 on first row
            s = fmaf(s, c2, 1.f);
#pragma unroll
            for (int k = 0; k < 4; ++k) {
                racc[k].x = fmaf(racc[k].x, c2, lv[k].x);
                racc[k].y = fmaf(racc[k].y, c2, lv[k].y);
                racc[k].z = fmaf(racc[k].z, c2, lv[k].z);
                racc[k].w = fmaf(racc[k].w, c2, lv[k].w);
            }
            m = acc;
        }
    }

    // 4-wave merge via LDS -> one partial per block
#pragma unroll
    for (int k = 0; k < 4; ++k)
        *(float4*)&lracc[w][(lane + 64 * k) * 4] = racc[k];
    if (lane == 0) { lms[w] = m; lms[4 + w] = s; }
    __syncthreads();

    const float mB = fmaxf(fmaxf(lms[0], lms[1]), fmaxf(lms[2], lms[3]));
    const float w0 = expf(lms[0] - mB), w1 = expf(lms[1] - mB);
    const float w2 = expf(lms[2] - mB), w3 = expf(lms[3] - mB);
    const float sB = lms[4] * w0 + lms[5] * w1 + lms[6] * w2 + lms[7] * w3;
    if (tid == 0) { pm[blockIdx.x] = mB; ps[blockIdx.x] = sB; }

    {
        const int col = tid * 4;
        const float4 a0 = *(const float4*)&lracc[0][col];
        const float4 a1 = *(const float4*)&lracc[1][col];
        const float4 a2 = *(const float4*)&lracc[2][col];
        const float4 a3 = *(const float4*)&lracc[3][col];
        float4 rb;
        rb.x = a0.x * w0 + a1.x * w1 + a2.x * w2 + a3.x * w3;
        rb.y = a0.y * w0 + a1.y * w1 + a2.y * w2 + a3.y * w3;
        rb.z = a0.z * w0 + a1.z * w1 + a2.z * w2 + a3.z * w3;
        rb.w = a0.w * w0 + a1.w * w1 + a2.w * w2 + a3.w * w3;
        ((float4*)(prb + (size_t)blockIdx.x * D))[tid] = rb;
    }

    // ---- election: last block of batch b finalizes r + alpha ----
    __threadfence();                         // release our prb/pm/ps/beta
    if (tid == 0) {
        const int old = atomicAdd(&cnt[b], 1);
        elect = (old == CPF - 1);
    }
    __syncthreads();
    if (!elect) return;
    __threadfence();                         // acquire others' writes

    float M = -INFINITY;
    for (int p = 0; p < CPF; ++p) M = fmaxf(M, pm[b * CPF + p]);
    float S = 0.f;
    for (int p = 0; p < CPF; ++p)
        S += expf(pm[b * CPF + p] - M) * ps[b * CPF + p];
    const float invS = 1.f / S;

    float4 racc2 = make_float4(0.f, 0.f, 0.f, 0.f);
    for (int p = 0; p < CPF; ++p) {
        const float wp = expf(pm[b * CPF + p] - M) * invS;
        const float4 v = ((const float4*)(prb + (size_t)(b * CPF + p) * D))[tid];
        racc2.x = fmaf(wp, v.x, racc2.x);
        racc2.y = fmaf(wp, v.y, racc2.y);
        racc2.z = fmaf(wp, v.z, racc2.z);
        racc2.w = fmaf(wp, v.w, racc2.w);
    }
    ((float4*)(r + (size_t)b * D))[tid] = racc2;

#pragma unroll
    for (int k = 0; k < 8; ++k) {
        const int t = k * 256 + tid;
        alpha[b * T + t] = expf(beta[b * T + t] - M) * invS;
    }
}

// ---------------------------------------------------------------------------
extern "C" void kernel_launch(void* const* d_in, const int* in_sizes, int n_in,
                              void* d_out, int out_size, void* d_ws, size_t ws_size,
                              hipStream_t stream) {
    const float* h    = (const float*)d_in[0];   // [B,T,D]
    const float* lstm = (const float*)d_in[1];   // [B,T,D]
    const float* mask = (const float*)d_in[2];   // [B,T,H]

    float* out   = (float*)d_out;
    float* r     = out;            // [B,1,D]
    float* alpha = out + B * D;    // [B,T]

    float* hpart = (float*)d_ws;                       // B*CPH*D = 2 MB
    float* pm    = hpart + (size_t)B * CPH * D;        // B*CPF
    float* ps    = pm + B * CPF;                       // B*CPF
    float* beta  = ps + B * CPF;                       // B*T
    float* prb   = beta + (size_t)B * T;               // B*CPF*D = 4 MB
    int*   cnt   = (int*)(prb + (size_t)B * CPF * D);  // B ints

    k_hpart<<<B * CPH, 256, 0, stream>>>(h, mask, hpart, cnt);
    k_fused<<<B * CPF, 256, 0, stream>>>(lstm, hpart, beta, pm, ps, prb,
                                         cnt, r, alpha);
}

// Round 8
// 129.879 us; speedup vs baseline: 2.5719x; 2.5719x over previous
//
#include <hip/hip_runtime.h>
#include <math.h>

// Problem constants: B=32, T=2048, H=512, D=2H=1024
constexpr int B = 32;
constexpr int T = 2048;
constexpr int H = 512;
constexpr int D = 2 * H;            // 1024
constexpr int CPH  = 16;            // hsum chunks per batch
constexpr int RWH  = T / CPH;       // 128 rows per hpart block
constexpr int CPF  = 32;            // fused chunks per batch
constexpr int RWF  = T / CPF;       // 64 rows per fused block
constexpr int ACB  = 4;             // alpha blocks per batch

// ---------------------------------------------------------------------------
// Kernel 1: hpart[b,c,d] = sum over 128 rows of h*mask2.  No atomics.
// grid = B*CPH = 512 blocks, 256 threads, thread owns float4 col tid.
// ---------------------------------------------------------------------------
__global__ void k_hpart(const float* __restrict__ h,
                        const float* __restrict__ mask,
                        float* __restrict__ hpart) {
    const int b   = blockIdx.x / CPH;
    const int c   = blockIdx.x % CPH;
    const int tid = threadIdx.x;
    const int t0  = c * RWH;

    const float4* hp = (const float4*)(h + ((size_t)b * T + t0) * D) + tid;
    const float4* mp = (const float4*)(mask + ((size_t)b * T + t0) * H) + (tid & 127);

    float4 acc = make_float4(0.f, 0.f, 0.f, 0.f);
    for (int t = 0; t < RWH; ++t) {
        float4 hv = hp[t * (D / 4)];
        float4 mv = mp[t * (H / 4)];
        acc.x += hv.x * mv.x;
        acc.y += hv.y * mv.y;
        acc.z += hv.z * mv.z;
        acc.w += hv.w * mv.w;
    }
    ((float4*)(hpart + (size_t)blockIdx.x * D))[tid] = acc;
}

// ---------------------------------------------------------------------------
// Kernel 2 (fused): reconstruct hsum from hpart (wave-split + LDS merge),
// single pass over lstm computing beta + online-softmax accumulation;
// 4-wave LDS merge -> ONE partial (m, s, racc[D]) per block.
// grid = B*CPF = 1024 blocks, 256 threads (4 waves).
// ---------------------------------------------------------------------------
__global__ void k_fused(const float* __restrict__ lstm,
                        const float* __restrict__ hpart,
                        float* __restrict__ beta,
                        float* __restrict__ pm,
                        float* __restrict__ ps,
                        float* __restrict__ prb) {
    const int b    = blockIdx.x / CPF;
    const int ch   = blockIdx.x % CPF;
    const int tid  = threadIdx.x;
    const int w    = tid >> 6;
    const int lane = tid & 63;

    __shared__ alignas(16) float lracc[4][D];   // 16 KB
    __shared__ float lms[8];

    // --- hsum prologue, wave-split: wave w sums partials {w, w+4, w+8, w+12}
    float4 hv[4] = {make_float4(0,0,0,0), make_float4(0,0,0,0),
                    make_float4(0,0,0,0), make_float4(0,0,0,0)};
    for (int p = w; p < CPH; p += 4) {
        const float4* pp = (const float4*)(hpart + (size_t)(b * CPH + p) * D);
#pragma unroll
        for (int k = 0; k < 4; ++k) {
            float4 v = pp[lane + 64 * k];
            hv[k].x += v.x; hv[k].y += v.y; hv[k].z += v.z; hv[k].w += v.w;
        }
    }
    // merge the 4 wave-partials through LDS; every wave needs the full sum
#pragma unroll
    for (int k = 0; k < 4; ++k)
        *(float4*)&lracc[w][(lane + 64 * k) * 4] = hv[k];
    __syncthreads();
#pragma unroll
    for (int k = 0; k < 4; ++k) {
        const int col = (lane + 64 * k) * 4;
        const float4 a0 = *(const float4*)&lracc[0][col];
        const float4 a1 = *(const float4*)&lracc[1][col];
        const float4 a2 = *(const float4*)&lracc[2][col];
        const float4 a3 = *(const float4*)&lracc[3][col];
        hv[k].x = (a0.x + a1.x) + (a2.x + a3.x);
        hv[k].y = (a0.y + a1.y) + (a2.y + a3.y);
        hv[k].z = (a0.z + a1.z) + (a2.z + a3.z);
        hv[k].w = (a0.w + a1.w) + (a2.w + a3.w);
    }
    __syncthreads();   // lracc is reused by the epilogue merge

    float m = -INFINITY, s = 0.f;
    float4 racc[4] = {make_float4(0,0,0,0), make_float4(0,0,0,0),
                      make_float4(0,0,0,0), make_float4(0,0,0,0)};
    const int t0 = ch * RWF;
    for (int i = 0; i < RWF / 4; ++i) {
        const int t = t0 + i * 4 + w;
        const float4* lp = (const float4*)(lstm + ((size_t)b * T + t) * D);
        float4 lv[4];
#pragma unroll
        for (int k = 0; k < 4; ++k) lv[k] = lp[lane + 64 * k];

        float acc = 0.f;
#pragma unroll
        for (int k = 0; k < 4; ++k)
            acc += lv[k].x * hv[k].x + lv[k].y * hv[k].y +
                   lv[k].z * hv[k].z + lv[k].w * hv[k].w;
#pragma unroll
        for (int o = 32; o >= 1; o >>= 1) acc += __shfl_xor(acc, o, 64);
        if (lane == 0) beta[b * T + t] = acc;

        if (acc <= m) {            // wave-uniform branch (acc reduced)
            const float e = expf(acc - m);
            s += e;
#pragma unroll
            for (int k = 0; k < 4; ++k) {
                racc[k].x = fmaf(e, lv[k].x, racc[k].x);
                racc[k].y = fmaf(e, lv[k].y, racc[k].y);
                racc[k].z = fmaf(e, lv[k].z, racc[k].z);
                racc[k].w = fmaf(e, lv[k].w, racc[k].w);
            }
        } else {
            const float c2 = expf(m - acc);   // expf(-inf)=0 on first row
            s = fmaf(s, c2, 1.f);
#pragma unroll
            for (int k = 0; k < 4; ++k) {
                racc[k].x = fmaf(racc[k].x, c2, lv[k].x);
                racc[k].y = fmaf(racc[k].y, c2, lv[k].y);
                racc[k].z = fmaf(racc[k].z, c2, lv[k].z);
                racc[k].w = fmaf(racc[k].w, c2, lv[k].w);
            }
            m = acc;
        }
    }

    // 4-wave merge via LDS -> one partial per block
#pragma unroll
    for (int k = 0; k < 4; ++k)
        *(float4*)&lracc[w][(lane + 64 * k) * 4] = racc[k];
    if (lane == 0) { lms[w] = m; lms[4 + w] = s; }
    __syncthreads();

    const float mB = fmaxf(fmaxf(lms[0], lms[1]), fmaxf(lms[2], lms[3]));
    const float w0 = expf(lms[0] - mB), w1 = expf(lms[1] - mB);
    const float w2 = expf(lms[2] - mB), w3 = expf(lms[3] - mB);
    const float sB = lms[4] * w0 + lms[5] * w1 + lms[6] * w2 + lms[7] * w3;
    if (tid == 0) { pm[blockIdx.x] = mB; ps[blockIdx.x] = sB; }

    const int col = tid * 4;
    const float4 a0 = *(const float4*)&lracc[0][col];
    const float4 a1 = *(const float4*)&lracc[1][col];
    const float4 a2 = *(const float4*)&lracc[2][col];
    const float4 a3 = *(const float4*)&lracc[3][col];
    float4 rb;
    rb.x = a0.x * w0 + a1.x * w1 + a2.x * w2 + a3.x * w3;
    rb.y = a0.y * w0 + a1.y * w1 + a2.y * w2 + a3.y * w3;
    rb.z = a0.z * w0 + a1.z * w1 + a2.z * w2 + a3.z * w3;
    rb.w = a0.w * w0 + a1.w * w1 + a2.w * w2 + a3.w * w3;
    ((float4*)(prb + (size_t)blockIdx.x * D))[tid] = rb;
}

// ---------------------------------------------------------------------------
// Kernel 3: finalize.  blocks [0,B): r[b,:] combine (no atomics — block owns
// its batch).  blocks [B, B+B*ACB): alpha.
// ---------------------------------------------------------------------------
__global__ void k_final(const float* __restrict__ pm,
                        const float* __restrict__ ps,
                        const float* __restrict__ prb,
                        const float* __restrict__ beta,
                        float* __restrict__ r,
                        float* __restrict__ alpha) {
    const int tid = threadIdx.x;

    if (blockIdx.x < B) {
        const int b = blockIdx.x;
        float M = -INFINITY;
        for (int p = 0; p < CPF; ++p) M = fmaxf(M, pm[b * CPF + p]);
        float S = 0.f;
        for (int p = 0; p < CPF; ++p)
            S += expf(pm[b * CPF + p] - M) * ps[b * CPF + p];
        const float invS = 1.f / S;

        float4 acc = make_float4(0.f, 0.f, 0.f, 0.f);
        for (int p = 0; p < CPF; ++p) {
            const float wp = expf(pm[b * CPF + p] - M) * invS;
            const float4 v = ((const float4*)(prb + (size_t)(b * CPF + p) * D))[tid];
            acc.x = fmaf(wp, v.x, acc.x);
            acc.y = fmaf(wp, v.y, acc.y);
            acc.z = fmaf(wp, v.z, acc.z);
            acc.w = fmaf(wp, v.w, acc.w);
        }
        ((float4*)(r + (size_t)b * D))[tid] = acc;
    } else {
        const int idx = blockIdx.x - B;
        const int b   = idx >> 2;          // / ACB
        const int q   = idx & (ACB - 1);
        float M = -INFINITY;
        for (int p = 0; p < CPF; ++p) M = fmaxf(M, pm[b * CPF + p]);
        float S = 0.f;
        for (int p = 0; p < CPF; ++p)
            S += expf(pm[b * CPF + p] - M) * ps[b * CPF + p];
        const float invS = 1.f / S;
#pragma unroll
        for (int k = 0; k < 2; ++k) {
            const int t = q * 512 + k * 256 + tid;
            alpha[b * T + t] = expf(beta[b * T + t] - M) * invS;
        }
    }
}

// ---------------------------------------------------------------------------
extern "C" void kernel_launch(void* const* d_in, const int* in_sizes, int n_in,
                              void* d_out, int out_size, void* d_ws, size_t ws_size,
                              hipStream_t stream) {
    const float* h    = (const float*)d_in[0];   // [B,T,D]
    const float* lstm = (const float*)d_in[1];   // [B,T,D]
    const float* mask = (const float*)d_in[2];   // [B,T,H]

    float* out   = (float*)d_out;
    float* r     = out;            // [B,1,D]
    float* alpha = out + B * D;    // [B,T]

    float* hpart = (float*)d_ws;                       // B*CPH*D = 2 MB
    float* pm    = hpart + (size_t)B * CPH * D;        // B*CPF
    float* ps    = pm + B * CPF;                       // B*CPF
    float* beta  = ps + B * CPF;                       // B*T
    float* prb   = beta + (size_t)B * T;               // B*CPF*D = 4 MB

    k_hpart<<<B * CPH,     256, 0, stream>>>(h, mask, hpart);
    k_fused<<<B * CPF,     256, 0, stream>>>(lstm, hpart, beta, pm, ps, prb);
    k_final<<<B + B * ACB, 256, 0, stream>>>(pm, ps, prb, beta, r, alpha);
}

// Round 9
// 129.301 us; speedup vs baseline: 2.5834x; 1.0045x over previous
//
#include <hip/hip_runtime.h>
#include <math.h>

// Problem constants: B=32, T=2048, H=512, D=2H=1024
constexpr int B = 32;
constexpr int T = 2048;
constexpr int H = 512;
constexpr int D = 2 * H;            // 1024
constexpr int CPH  = 16;            // hsum chunks per batch
constexpr int RWH  = T / CPH;       // 128 rows per hpart block
constexpr int CPF  = 32;            // fused chunks per batch
constexpr int RWF  = T / CPF;       // 64 rows per fused block
constexpr int ACB  = 4;             // alpha blocks per batch

// ---------------------------------------------------------------------------
// Kernel 1: hpart[b,c,d] = sum over 128 rows of h*mask2.  No atomics.
// grid = B*CPH = 512 blocks, 256 threads, thread owns float4 col tid.
// ---------------------------------------------------------------------------
__global__ void k_hpart(const float* __restrict__ h,
                        const float* __restrict__ mask,
                        float* __restrict__ hpart) {
    const int b   = blockIdx.x / CPH;
    const int c   = blockIdx.x % CPH;
    const int tid = threadIdx.x;
    const int t0  = c * RWH;

    const float4* hp = (const float4*)(h + ((size_t)b * T + t0) * D) + tid;
    const float4* mp = (const float4*)(mask + ((size_t)b * T + t0) * H) + (tid & 127);

    float4 acc = make_float4(0.f, 0.f, 0.f, 0.f);
#pragma unroll 4
    for (int t = 0; t < RWH; ++t) {
        float4 hv = hp[t * (D / 4)];
        float4 mv = mp[t * (H / 4)];
        acc.x += hv.x * mv.x;
        acc.y += hv.y * mv.y;
        acc.z += hv.z * mv.z;
        acc.w += hv.w * mv.w;
    }
    ((float4*)(hpart + (size_t)blockIdx.x * D))[tid] = acc;
}

// ---------------------------------------------------------------------------
// Kernel 2 (fused): reconstruct hsum from hpart (wave-split + LDS merge),
// single pass over lstm computing beta + online-softmax accumulation;
// 4-wave LDS merge -> ONE partial (m, s, racc[D]) per block.
// grid = B*CPF = 1024 blocks, 256 threads (4 waves).
// ---------------------------------------------------------------------------
__global__ void k_fused(const float* __restrict__ lstm,
                        const float* __restrict__ hpart,
                        float* __restrict__ beta,
                        float* __restrict__ pm,
                        float* __restrict__ ps,
                        float* __restrict__ prb) {
    const int b    = blockIdx.x / CPF;
    const int ch   = blockIdx.x % CPF;
    const int tid  = threadIdx.x;
    const int w    = tid >> 6;
    const int lane = tid & 63;

    __shared__ alignas(16) float lracc[4][D];   // 16 KB
    __shared__ float lms[8];

    // --- hsum prologue, wave-split: wave w sums partials {w, w+4, w+8, w+12}
    float4 hv[4] = {make_float4(0,0,0,0), make_float4(0,0,0,0),
                    make_float4(0,0,0,0), make_float4(0,0,0,0)};
    for (int p = w; p < CPH; p += 4) {
        const float4* pp = (const float4*)(hpart + (size_t)(b * CPH + p) * D);
#pragma unroll
        for (int k = 0; k < 4; ++k) {
            float4 v = pp[lane + 64 * k];
            hv[k].x += v.x; hv[k].y += v.y; hv[k].z += v.z; hv[k].w += v.w;
        }
    }
    // merge the 4 wave-partials through LDS; every wave needs the full sum
#pragma unroll
    for (int k = 0; k < 4; ++k)
        *(float4*)&lracc[w][(lane + 64 * k) * 4] = hv[k];
    __syncthreads();
#pragma unroll
    for (int k = 0; k < 4; ++k) {
        const int col = (lane + 64 * k) * 4;
        const float4 a0 = *(const float4*)&lracc[0][col];
        const float4 a1 = *(const float4*)&lracc[1][col];
        const float4 a2 = *(const float4*)&lracc[2][col];
        const float4 a3 = *(const float4*)&lracc[3][col];
        hv[k].x = (a0.x + a1.x) + (a2.x + a3.x);
        hv[k].y = (a0.y + a1.y) + (a2.y + a3.y);
        hv[k].z = (a0.z + a1.z) + (a2.z + a3.z);
        hv[k].w = (a0.w + a1.w) + (a2.w + a3.w);
    }
    __syncthreads();   // lracc is reused by the epilogue merge

    float m = -INFINITY, s = 0.f;
    float4 racc[4] = {make_float4(0,0,0,0), make_float4(0,0,0,0),
                      make_float4(0,0,0,0), make_float4(0,0,0,0)};
    const int t0 = ch * RWF;
    for (int i = 0; i < RWF / 4; ++i) {
        const int t = t0 + i * 4 + w;
        const float4* lp = (const float4*)(lstm + ((size_t)b * T + t) * D);
        float4 lv[4];
#pragma unroll
        for (int k = 0; k < 4; ++k) lv[k] = lp[lane + 64 * k];

        float acc = 0.f;
#pragma unroll
        for (int k = 0; k < 4; ++k)
            acc += lv[k].x * hv[k].x + lv[k].y * hv[k].y +
                   lv[k].z * hv[k].z + lv[k].w * hv[k].w;
#pragma unroll
        for (int o = 32; o >= 1; o >>= 1) acc += __shfl_xor(acc, o, 64);
        if (lane == 0) beta[b * T + t] = acc;

        if (acc <= m) {            // wave-uniform branch (acc reduced)
            const float e = expf(acc - m);
            s += e;
#pragma unroll
            for (int k = 0; k < 4; ++k) {
                racc[k].x = fmaf(e, lv[k].x, racc[k].x);
                racc[k].y = fmaf(e, lv[k].y, racc[k].y);
                racc[k].z = fmaf(e, lv[k].z, racc[k].z);
                racc[k].w = fmaf(e, lv[k].w, racc[k].w);
            }
        } else {
            const float c2 = expf(m - acc);   // expf(-inf)=0 on first row
            s = fmaf(s, c2, 1.f);
#pragma unroll
            for (int k = 0; k < 4; ++k) {
                racc[k].x = fmaf(racc[k].x, c2, lv[k].x);
                racc[k].y = fmaf(racc[k].y, c2, lv[k].y);
                racc[k].z = fmaf(racc[k].z, c2, lv[k].z);
                racc[k].w = fmaf(racc[k].w, c2, lv[k].w);
            }
            m = acc;
        }
    }

    // 4-wave merge via LDS -> one partial per block
#pragma unroll
    for (int k = 0; k < 4; ++k)
        *(float4*)&lracc[w][(lane + 64 * k) * 4] = racc[k];
    if (lane == 0) { lms[w] = m; lms[4 + w] = s; }
    __syncthreads();

    const float mB = fmaxf(fmaxf(lms[0], lms[1]), fmaxf(lms[2], lms[3]));
    const float w0 = expf(lms[0] - mB), w1 = expf(lms[1] - mB);
    const float w2 = expf(lms[2] - mB), w3 = expf(lms[3] - mB);
    const float sB = lms[4] * w0 + lms[5] * w1 + lms[6] * w2 + lms[7] * w3;
    if (tid == 0) { pm[blockIdx.x] = mB; ps[blockIdx.x] = sB; }

    const int col = tid * 4;
    const float4 a0 = *(const float4*)&lracc[0][col];
    const float4 a1 = *(const float4*)&lracc[1][col];
    const float4 a2 = *(const float4*)&lracc[2][col];
    const float4 a3 = *(const float4*)&lracc[3][col];
    float4 rb;
    rb.x = a0.x * w0 + a1.x * w1 + a2.x * w2 + a3.x * w3;
    rb.y = a0.y * w0 + a1.y * w1 + a2.y * w2 + a3.y * w3;
    rb.z = a0.z * w0 + a1.z * w1 + a2.z * w2 + a3.z * w3;
    rb.w = a0.w * w0 + a1.w * w1 + a2.w * w2 + a3.w * w3;
    ((float4*)(prb + (size_t)blockIdx.x * D))[tid] = rb;
}

// ---------------------------------------------------------------------------
// Kernel 3: finalize.  blocks [0,B): r[b,:] combine (no atomics — block owns
// its batch).  blocks [B, B+B*ACB): alpha.
// ---------------------------------------------------------------------------
__global__ void k_final(const float* __restrict__ pm,
                        const float* __restrict__ ps,
                        const float* __restrict__ prb,
                        const float* __restrict__ beta,
                        float* __restrict__ r,
                        float* __restrict__ alpha) {
    const int tid = threadIdx.x;

    if (blockIdx.x < B) {
        const int b = blockIdx.x;
        float M = -INFINITY;
        for (int p = 0; p < CPF; ++p) M = fmaxf(M, pm[b * CPF + p]);
        float S = 0.f;
        for (int p = 0; p < CPF; ++p)
            S += expf(pm[b * CPF + p] - M) * ps[b * CPF + p];
        const float invS = 1.f / S;

        float4 acc = make_float4(0.f, 0.f, 0.f, 0.f);
        for (int p = 0; p < CPF; ++p) {
            const float wp = expf(pm[b * CPF + p] - M) * invS;
            const float4 v = ((const float4*)(prb + (size_t)(b * CPF + p) * D))[tid];
            acc.x = fmaf(wp, v.x, acc.x);
            acc.y = fmaf(wp, v.y, acc.y);
            acc.z = fmaf(wp, v.z, acc.z);
            acc.w = fmaf(wp, v.w, acc.w);
        }
        ((float4*)(r + (size_t)b * D))[tid] = acc;
    } else {
        const int idx = blockIdx.x - B;
        const int b   = idx >> 2;          // / ACB
        const int q   = idx & (ACB - 1);
        float M = -INFINITY;
        for (int p = 0; p < CPF; ++p) M = fmaxf(M, pm[b * CPF + p]);
        float S = 0.f;
        for (int p = 0; p < CPF; ++p)
            S += expf(pm[b * CPF + p] - M) * ps[b * CPF + p];
        const float invS = 1.f / S;
#pragma unroll
        for (int k = 0; k < 2; ++k) {
            const int t = q * 512 + k * 256 + tid;
            alpha[b * T + t] = expf(beta[b * T + t] - M) * invS;
        }
    }
}

// ---------------------------------------------------------------------------
extern "C" void kernel_launch(void* const* d_in, const int* in_sizes, int n_in,
                              void* d_out, int out_size, void* d_ws, size_t ws_size,
                              hipStream_t stream) {
    const float* h    = (const float*)d_in[0];   // [B,T,D]
    const float* lstm = (const float*)d_in[1];   // [B,T,D]
    const float* mask = (const float*)d_in[2];   // [B,T,H]

    float* out   = (float*)d_out;
    float* r     = out;            // [B,1,D]
    float* alpha = out + B * D;    // [B,T]

    float* hpart = (float*)d_ws;                       // B*CPH*D = 2 MB
    float* pm    = hpart + (size_t)B * CPH * D;        // B*CPF
    float* ps    = pm + B * CPF;                       // B*CPF
    float* beta  = ps + B * CPF;                       // B*T
    float* prb   = beta + (size_t)B * T;               // B*CPF*D = 4 MB

    k_hpart<<<B * CPH,     256, 0, stream>>>(h, mask, hpart);
    k_fused<<<B * CPF,     256, 0, stream>>>(lstm, hpart, beta, pm, ps, prb);
    k_final<<<B + B * ACB, 256, 0, stream>>>(pm, ps, prb, beta, r, alpha);
}